// Round 8
// baseline (209.274 us; speedup 1.0000x reference)
//
#include <hip/hip_runtime.h>

#define NROWS 4096
#define NDOM 8

typedef short short8 __attribute__((ext_vector_type(8)));
typedef float floatx4 __attribute__((ext_vector_type(4)));
typedef unsigned short ushort8v __attribute__((ext_vector_type(8)));

__device__ __forceinline__ unsigned short f2bf(float f) {
    union { float f; unsigned u; } v; v.f = f;
    unsigned r = v.u + 0x7FFFu + ((v.u >> 16) & 1u);  // RNE
    return (unsigned short)(r >> 16);
}

// async global->LDS, 16B per lane; dest = wave-uniform base + lane*16,
// source address may be per-lane (gather is legal on the source side).
__device__ __forceinline__ void dma16(const void* g, void* l) {
    __builtin_amdgcn_global_load_lds(
        (const __attribute__((address_space(1))) unsigned*)g,
        (__attribute__((address_space(3))) unsigned*)l, 16, 0, 0);
}

// counted vmcnt wait (immediate must be a literal in the asm string)
template <int N>
__device__ __forceinline__ void wait_vmcnt() {
    static_assert(N == 0 || N == 2 || N == 3 || N == 4 || N == 6 || N == 8, "unsupported vmcnt");
    if constexpr (N == 0) asm volatile("s_waitcnt vmcnt(0)" ::: "memory");
    else if constexpr (N == 2) asm volatile("s_waitcnt vmcnt(2)" ::: "memory");
    else if constexpr (N == 3) asm volatile("s_waitcnt vmcnt(3)" ::: "memory");
    else if constexpr (N == 4) asm volatile("s_waitcnt vmcnt(4)" ::: "memory");
    else if constexpr (N == 6) asm volatile("s_waitcnt vmcnt(6)" ::: "memory");
    else if constexpr (N == 8) asm volatile("s_waitcnt vmcnt(8)" ::: "memory");
}

// ---------------------------------------------------------------------------
// NEW weff: NO LDS, NO transpose. Output layout is fragment-ready subtiled
// [d][N/16][K/8][16][8]: element (d,n,k) at
//   d*(N/16)*K*16 + (n/16)*K*16 + (k/8)*128 + (n%16)*8 + (k%8).
// Round-7 PMC: old LDS-transpose version was latency*occupancy-bound
// (24.8% occ, 2.3TB/s, VALU 5.5% -> nothing saturated; 32KB LDS + barrier
// structure capped resident waves at 8/CU = exactly 2.3TB/s by Little's law).
// Here: thread computes an 8k x 16n micro-tile: 32 coalesced float4 loads
// (lanes 0-3 cover 256B of one k-row), 256B contiguous store. LDS -> 12.4KB
// (sort only) -> occupancy cap 32 waves/CU.
// Tile = (d, 64 n, 512 k); 256 threads = 4 ng x 64 kg micro-tiles.
// ---------------------------------------------------------------------------
template <int K, int N>
__device__ __forceinline__ void weff_tile_nolds(const float* __restrict__ sk,
                                                const float* __restrict__ dk,
                                                unsigned short* __restrict__ wt,
                                                int local) {
    constexpr int KT = K / 512;            // k-tiles per layer (1 or 2)
    const int d = local & 7;
    const int rest = local >> 3;
    const int kt = rest & (KT - 1);
    const int nt = rest / KT;
    const int k0 = kt * 512;
    const int n0 = nt * 64;
    const int t = threadIdx.x;
    const int ng = t & 3;                  // 16-n window
    const int kg = t >> 2;                 // 8-k chunk [0,64)
    const int kb = k0 + kg * 8;
    const int nb = n0 + ng * 16;

    unsigned short ob[16][8];              // [nn][i] bf16 products
#pragma unroll
    for (int i = 0; i < 8; ++i) {
        const int k = kb + i;
        const float* srow = sk + (size_t)k * N + nb;
        const float* drow = dk + ((size_t)d * K + k) * N + nb;
#pragma unroll
        for (int q = 0; q < 4; ++q) {
            floatx4 sv = *(const floatx4*)(srow + q * 4);
            floatx4 dv = *(const floatx4*)(drow + q * 4);
#pragma unroll
            for (int j = 0; j < 4; ++j) ob[q * 4 + j][i] = f2bf(sv[j] * dv[j]);
        }
    }
    unsigned short* dst = wt + ((size_t)d * (N / 16) + (nb >> 4)) * ((size_t)K * 16)
                             + (size_t)(kb >> 3) * 128;
#pragma unroll
    for (int nn = 0; nn < 16; ++nn)
        *(ushort8v*)(dst + nn * 8) = *(ushort8v*)ob[nn];
}

struct SortMem {
    unsigned short cnt[256][NDOM];
    int base[256][NDOM];
    int dom_total[NDOM];
    int dom_off[NDOM + 1];
};

// ---------------------------------------------------------------------------
// Fused precompute dispatch (weff blocks first — they are the long pole):
//   blocks [0,256)    : w0t (N=1024,K=1024: 16nt x 2kt x 8d)
//   blocks [256,384)  : w1t (N=512, K=1024:  8nt x 2kt x 8d)
//   blocks [384,416)  : w2t (N=256, K=512 :  4nt x 1kt x 8d)
//   blocks [416,672)  : xb = bf16(x), original row order
//   block 672         : counting sort -> offsets, rowidx
// ---------------------------------------------------------------------------
__global__ void precompute_kernel(const float* __restrict__ x,
                                  const int* __restrict__ ind,
                                  const float* __restrict__ sk0, const float* __restrict__ dk0,
                                  const float* __restrict__ sk1, const float* __restrict__ dk1,
                                  const float* __restrict__ sk2, const float* __restrict__ dk2,
                                  unsigned short* __restrict__ xb,
                                  unsigned short* __restrict__ w0t,
                                  unsigned short* __restrict__ w1t,
                                  unsigned short* __restrict__ w2t,
                                  int* __restrict__ offsets,
                                  int* __restrict__ rowidx) {
    __shared__ SortMem smem;               // 12.4KB, used only by the sort block

    const int b = blockIdx.x;
    const int t = threadIdx.x;

    if (b < 256) {
        weff_tile_nolds<1024, 1024>(sk0, dk0, w0t, b);
    } else if (b < 256 + 128) {
        weff_tile_nolds<1024, 512>(sk1, dk1, w1t, b - 256);
    } else if (b < 256 + 128 + 32) {
        weff_tile_nolds<512, 256>(sk2, dk2, w2t, b - (256 + 128));
    } else if (b < 256 + 128 + 32 + 256) {
        // xb: bf16(x) in original row order, fully coalesced both sides
        const int bb = b - (256 + 128 + 32);
#pragma unroll
        for (int pass = 0; pass < 8; ++pass) {
            int row = bb * 16 + pass * 2 + (t >> 7);
            int ch = t & 127;                       // 8-elem chunk
            const float* src = x + (size_t)row * 1024 + ch * 8;
            floatx4 v0 = *(const floatx4*)src;
            floatx4 v1 = *(const floatx4*)(src + 4);
            unsigned short o[8];
            o[0] = f2bf(v0[0]); o[1] = f2bf(v0[1]); o[2] = f2bf(v0[2]); o[3] = f2bf(v0[3]);
            o[4] = f2bf(v1[0]); o[5] = f2bf(v1[1]); o[6] = f2bf(v1[2]); o[7] = f2bf(v1[3]);
            *(ushort8v*)(xb + (size_t)row * 1024 + ch * 8) = *(ushort8v*)o;
        }
    } else {
        // deterministic stable counting sort (pure function of `ind`)
        int myind[16];
#pragma unroll
        for (int i = 0; i < 16; ++i) myind[i] = ind[t * 16 + i];
        unsigned short c[NDOM];
#pragma unroll
        for (int d = 0; d < NDOM; ++d) c[d] = 0;
#pragma unroll
        for (int i = 0; i < 16; ++i) c[myind[i]]++;
#pragma unroll
        for (int d = 0; d < NDOM; ++d) smem.cnt[t][d] = c[d];
        __syncthreads();
        if (t < NDOM) {
            int acc = 0;
            for (int ch = 0; ch < 256; ++ch) { smem.base[ch][t] = acc; acc += smem.cnt[ch][t]; }
            smem.dom_total[t] = acc;
        }
        __syncthreads();
        if (t == 0) {
            int acc = 0;
            for (int d = 0; d < NDOM; ++d) { smem.dom_off[d] = acc; acc += smem.dom_total[d]; }
            smem.dom_off[NDOM] = acc;
        }
        __syncthreads();
        int pos[NDOM];
#pragma unroll
        for (int d = 0; d < NDOM; ++d) pos[d] = smem.dom_off[d] + smem.base[t][d];
#pragma unroll
        for (int i = 0; i < 16; ++i) {
            int dm = myind[i];
            rowidx[pos[dm]++] = t * 16 + i;
        }
        if (t <= NDOM) offsets[t] = smem.dom_off[t];
    }
}

// ---------------------------------------------------------------------------
// Grouped GEMM: 2x2 waves, wave tile (FM*16)x(FN*16), double-buffered LDS,
// counted-vmcnt pipeline (round-2-verified). W operand now comes from the
// subtiled global layout [d][N/16][K/8][16][8]:
//   - DMA unit u (= w*WI+j) covers a contiguous 512-elem half-n-group
//     (no source XOR needed); per k-tile advance = kt*1024 elems.
//   - frag read: group (wx*FN+j), chunk c=kk*4+quad, col lm:
//     Ws[goff*1024 + c*128 + lm*8] — 16 lanes read 256B contiguous (~2-way
//     bank aliasing = free). Logical fragment content identical to before.
// A path (xb rows + chunk-XOR) unchanged.
// ---------------------------------------------------------------------------
template <int FM, int FN, int MSLOTS, int K, int N, bool GATHER, bool SCATTER>
__launch_bounds__(256)
__global__ void star_gemm(const unsigned short* __restrict__ Ab,
                          const unsigned short* __restrict__ Wt,
                          const float* __restrict__ sb,
                          const float* __restrict__ db,
                          float* __restrict__ OutF,
                          unsigned short* __restrict__ OutB,
                          const int* __restrict__ offsets,
                          const int* __restrict__ rowidx) {
    constexpr int BM = 32 * FM;
    constexpr int BN = 32 * FN;
    constexpr int NK = K / 64;     // 64-wide k tiles (NK even)
    constexpr int AI = BM / 32;    // A dma instrs per wave (1KB each)
    constexpr int WI = BN / 32;    // W dma instrs per wave
    constexpr int CNT = AI + WI;   // dma batch size per wave per k-tile

    __shared__ __align__(128) unsigned short As[2][BM * 64];
    __shared__ __align__(128) unsigned short Ws[2][BN * 64];

    const int gid = blockIdx.x;
    const int d = gid & 7;                      // domain -> XCD round-robin
    const int mslot = (gid >> 3) % MSLOTS;
    const int n0 = (gid / (8 * MSLOTS)) * BN;

    const int bstart = offsets[d];
    const int bend = offsets[d + 1];
    const int bsize = bend - bstart;

    const int tid = threadIdx.x;
    const int lane = tid & 63;
    const int w = tid >> 6;
    const int wy = w >> 1;
    const int wx = w & 1;
    const int lm = lane & 15;
    const int quad = lane >> 4;

    const int lrow = lane >> 3;    // A DMA: row within 8-row group
    const int phys = lane & 7;     // A DMA: physical LDS chunk

    float bias[FN];
#pragma unroll
    for (int j = 0; j < FN; ++j) {
        int n = n0 + wx * FN * 16 + j * 16 + lm;
        bias[j] = sb[n] + db[d * N + n];
    }

    // W dma sources (loop-invariant): unit u covers contiguous 512 elems
    const unsigned short* wsrc[WI];
#pragma unroll
    for (int j = 0; j < WI; ++j) {
        int u = w * WI + j;
        wsrc[j] = Wt + ((size_t)d * (N / 16) + (n0 >> 4) + (u >> 1)) * ((size_t)K * 16)
                     + (u & 1) * 512 + lane * 8;
    }

    for (int mt = mslot; mt * BM < bsize; mt += MSLOTS) {
        const int row_start = bstart + mt * BM;

        const unsigned short* asrc[AI];
#pragma unroll
        for (int j = 0; j < AI; ++j) {
            int m0 = (w * AI + j) * 8;
            int mm = m0 + lrow;
            int ch = phys ^ (mm & 7);
            int p = row_start + mm; if (p >= bend) p = bend - 1;
            int src = GATHER ? rowidx[p] : p;
            asrc[j] = Ab + (size_t)src * K + ch * 8;
        }

        auto dma_tiles = [&](int kt, int buf) {
            const int k0 = kt * 64;
#pragma unroll
            for (int j = 0; j < AI; ++j)
                dma16(asrc[j] + k0, &As[buf][(w * AI + j) * 512]);
#pragma unroll
            for (int j = 0; j < WI; ++j)
                dma16(wsrc[j] + kt * 1024, &Ws[buf][(w * WI + j) * 512]);
        };

        dma_tiles(0, 0);                       // prologue batch in flight

        floatx4 acc[FM][FN];
#pragma unroll
        for (int i = 0; i < FM; ++i)
#pragma unroll
            for (int j = 0; j < FN; ++j) acc[i][j] = floatx4{0.f, 0.f, 0.f, 0.f};

#pragma unroll 2
        for (int kt = 0; kt < NK; ++kt) {
            const int buf = kt & 1;
            if (kt + 1 < NK) {
                dma_tiles(kt + 1, 1 - buf);    // issue next batch FIRST
                wait_vmcnt<CNT>();             // tile kt arrived; kt+1 stays in flight
            } else {
                wait_vmcnt<0>();               // epilogue drain
            }
            __builtin_amdgcn_s_barrier();      // tile kt visible to all waves
            asm volatile("" ::: "memory");     // no hoisting reads above barrier

            short8 av[2][FM], wv[2][FN];
#pragma unroll
            for (int kk = 0; kk < 2; ++kk) {
#pragma unroll
                for (int i = 0; i < FM; ++i) {
                    int m = wy * FM * 16 + i * 16 + lm;
                    int pc = (kk * 4 + quad) ^ (m & 7);
                    av[kk][i] = *(const short8*)&As[buf][m * 64 + pc * 8];
                }
#pragma unroll
                for (int j = 0; j < FN; ++j) {
                    int goff = (wx * FN + j) * 1024;
                    int c = kk * 4 + quad;
                    wv[kk][j] = *(const short8*)&Ws[buf][goff + c * 128 + lm * 8];
                }
            }
            asm volatile("s_waitcnt lgkmcnt(0)" ::: "memory");  // frag regs live
            __builtin_amdgcn_sched_barrier(0);
            __builtin_amdgcn_s_barrier();      // all readers done; buf reusable
            asm volatile("" ::: "memory");

            __builtin_amdgcn_s_setprio(1);
#pragma unroll
            for (int kk = 0; kk < 2; ++kk)
#pragma unroll
                for (int i = 0; i < FM; ++i)
#pragma unroll
                    for (int j = 0; j < FN; ++j)
                        acc[i][j] = __builtin_amdgcn_mfma_f32_16x16x32_bf16(
                            av[kk][i], wv[kk][j], acc[i][j], 0, 0, 0);
            __builtin_amdgcn_s_setprio(0);
        }

        // epilogue: bias + relu; C layout col=lane&15, row=quad*4+reg
#pragma unroll
        for (int i = 0; i < FM; ++i) {
#pragma unroll
            for (int rg = 0; rg < 4; ++rg) {
                int m = wy * FM * 16 + i * 16 + quad * 4 + rg;
                int p = row_start + m;
                if (p < bend) {
                    if constexpr (SCATTER) {
                        int orow = rowidx[p];
#pragma unroll
                        for (int j = 0; j < FN; ++j) {
                            int n = n0 + wx * FN * 16 + j * 16 + lm;
                            float v = acc[i][j][rg] + bias[j];
                            OutF[(size_t)orow * N + n] = v > 0.f ? v : 0.f;
                        }
                    } else {
#pragma unroll
                        for (int j = 0; j < FN; ++j) {
                            int n = n0 + wx * FN * 16 + j * 16 + lm;
                            float v = acc[i][j][rg] + bias[j];
                            OutB[(size_t)p * N + n] = f2bf(v > 0.f ? v : 0.f);
                        }
                    }
                }
            }
        }
    }
}

extern "C" void kernel_launch(void* const* d_in, const int* in_sizes, int n_in,
                              void* d_out, int out_size, void* d_ws, size_t ws_size,
                              hipStream_t stream) {
    const float* x = (const float*)d_in[0];
    const int* ind = (const int*)d_in[1];
    const float* sk0 = (const float*)d_in[2];
    const float* sb0 = (const float*)d_in[3];
    const float* dk0 = (const float*)d_in[4];
    const float* db0 = (const float*)d_in[5];
    const float* sk1 = (const float*)d_in[6];
    const float* sb1 = (const float*)d_in[7];
    const float* dk1 = (const float*)d_in[8];
    const float* db1 = (const float*)d_in[9];
    const float* sk2 = (const float*)d_in[10];
    const float* sb2 = (const float*)d_in[11];
    const float* dk2 = (const float*)d_in[12];
    const float* db2 = (const float*)d_in[13];
    float* out = (float*)d_out;

    // workspace layout (~46 MB); w?t now in subtiled [d][N/16][K/8][16][8]
    char* ws = (char*)d_ws;
    int* offsets = (int*)ws;                                      // 64 B
    int* rowidx = (int*)(ws + 256);                               // 16 KB
    unsigned short* xb  = (unsigned short*)(ws + 32768);          // 8 MB  bf16 x, ORIGINAL order
    unsigned short* h1  = xb + (size_t)NROWS * 1024;              // 8 MB  bucket order
    unsigned short* h2  = h1 + (size_t)NROWS * 1024;              // 4 MB  bucket order
    unsigned short* w0t = h2 + (size_t)NROWS * 512;               // 16 MB
    unsigned short* w1t = w0t + (size_t)NDOM * 1024 * 1024;       // 8 MB
    unsigned short* w2t = w1t + (size_t)NDOM * 512 * 1024;        // 2 MB

    // fused: 3x weff (no-LDS) + xb cvt + bucket sort (1 dispatch)
    precompute_kernel<<<256 + 128 + 32 + 256 + 1, 256, 0, stream>>>(
        x, ind, sk0, dk0, sk1, dk1, sk2, dk2, xb, w0t, w1t, w2t, offsets, rowidx);

    // L0: 64x64 tiles, 8d x 8m x 16n = 1024 blocks, rowidx-gather DMA
    star_gemm<2, 2, 8, 1024, 1024, true, false><<<1024, 256, 0, stream>>>(
        xb, w0t, sb0, db0, nullptr, h1, offsets, rowidx);
    // L1: 64x64 tiles, 8d x 8m x 8n = 512 blocks
    star_gemm<2, 2, 8, 1024, 512, false, false><<<512, 256, 0, stream>>>(
        h1, w1t, sb1, db1, nullptr, h2, offsets, rowidx);
    // L2: 32x64 tiles, 8d x 16m x 4n = 512 blocks (scatter to fp32 out)
    star_gemm<1, 2, 16, 512, 256, false, true><<<512, 256, 0, stream>>>(
        h2, w2t, sb2, db2, out, nullptr, offsets, rowidx);
}

// Round 9
// 188.803 us; speedup vs baseline: 1.1084x; 1.1084x over previous
//
#include <hip/hip_runtime.h>

#define NROWS 4096
#define NDOM 8

typedef short short8 __attribute__((ext_vector_type(8)));
typedef float floatx4 __attribute__((ext_vector_type(4)));
typedef unsigned short ushort8v __attribute__((ext_vector_type(8)));

__device__ __forceinline__ unsigned short f2bf(float f) {
    union { float f; unsigned u; } v; v.f = f;
    unsigned r = v.u + 0x7FFFu + ((v.u >> 16) & 1u);  // RNE
    return (unsigned short)(r >> 16);
}

// async global->LDS, 16B per lane; dest = wave-uniform base + lane*16,
// source address may be per-lane (gather is legal on the source side).
__device__ __forceinline__ void dma16(const void* g, void* l) {
    __builtin_amdgcn_global_load_lds(
        (const __attribute__((address_space(1))) unsigned*)g,
        (__attribute__((address_space(3))) unsigned*)l, 16, 0, 0);
}

// ---------------------------------------------------------------------------
// Fused precompute dispatch (round-0-verified structure):
//   blocks [0,256)        : xb = bf16(x), ORIGINAL row order
//   blocks [256,768)      : w0t = bf16(sk0*dk0) transposed [d][n][k]
//   blocks [768,1024)     : w1t
//   blocks [1024,1088)    : w2t
//   block 1088            : deterministic counting-sort -> offsets, rowidx
// Single delta vs round 0: LDS union (transpose buffer | sort arrays),
// 44KB -> 32KB per block, occupancy cap 3 -> 5 blocks/CU (R2-verified safe).
// ---------------------------------------------------------------------------

template <int K, int N>
__device__ __forceinline__ void weff_tile(const float* __restrict__ sk,
                                          const float* __restrict__ dk,
                                          unsigned short* __restrict__ wt,
                                          unsigned short* __restrict__ lds,
                                          int local) {
    // tile = (domain d, 64 n, 256 k)
    const int d = local & 7;
    const int rest = local >> 3;
    const int k0 = (rest & (K / 256 - 1)) * 256;
    const int n0 = (rest / (K / 256)) * 64;
    const int t = threadIdx.x;

    // phase A: read n-coalesced, write LDS [n][k] with chunk-XOR swizzle
    const int n = t & 63;
    const int kg = (t >> 6) * 64;          // 4 k-groups of 64
#pragma unroll
    for (int c8 = 0; c8 < 8; ++c8) {       // 8 chunks of 8 k
        const int kb = k0 + kg + c8 * 8;
        unsigned short wb[8];
#pragma unroll
        for (int i = 0; i < 8; ++i) {
            int k = kb + i;
            wb[i] = f2bf(sk[(size_t)k * N + n0 + n] * dk[((size_t)d * K + k) * N + n0 + n]);
        }
        int ch = (kg + c8 * 8) >> 3;       // chunk index 0..31
        int phys = ch ^ (n & 31);
        *(ushort8v*)&lds[n * 256 + phys * 8] = *(ushort8v*)wb;
    }
    __syncthreads();

    // phase B: read LDS along k, store global [n][k] coalesced
#pragma unroll
    for (int it = 0; it < 4; ++it) {
        const int nn = (t >> 4) + it * 16;
        const int c = t & 15;              // 32B unit = 2 chunks
        ushort8v a = *(ushort8v*)&lds[nn * 256 + ((2 * c) ^ (nn & 31)) * 8];
        ushort8v b = *(ushort8v*)&lds[nn * 256 + ((2 * c + 1) ^ (nn & 31)) * 8];
        unsigned short* dst = wt + ((size_t)d * N + n0 + nn) * K + k0 + c * 16;
        *(ushort8v*)dst = a;
        *(ushort8v*)(dst + 8) = b;
    }
}

__global__ void precompute_kernel(const float* __restrict__ x,
                                  const int* __restrict__ ind,
                                  const float* __restrict__ sk0, const float* __restrict__ dk0,
                                  const float* __restrict__ sk1, const float* __restrict__ dk1,
                                  const float* __restrict__ sk2, const float* __restrict__ dk2,
                                  unsigned short* __restrict__ xb,
                                  unsigned short* __restrict__ w0t,
                                  unsigned short* __restrict__ w1t,
                                  unsigned short* __restrict__ w2t,
                                  int* __restrict__ offsets,
                                  int* __restrict__ rowidx) {
    __shared__ union SMem {
        unsigned short wtile[64 * 256];                 // 32KB transpose buffer
        struct {
            unsigned short cnt[256][NDOM];
            int base[256][NDOM];
            int dom_total[NDOM];
            int dom_off[NDOM + 1];
        } sort;
    } smem;

    const int b = blockIdx.x;
    const int t = threadIdx.x;

    if (b < 256) {
        // xb: bf16(x) in original row order, fully coalesced both sides
#pragma unroll
        for (int pass = 0; pass < 8; ++pass) {
            int row = b * 16 + pass * 2 + (t >> 7);
            int ch = t & 127;                       // 8-elem chunk
            const float* src = x + (size_t)row * 1024 + ch * 8;
            floatx4 v0 = *(const floatx4*)src;
            floatx4 v1 = *(const floatx4*)(src + 4);
            unsigned short o[8];
            o[0] = f2bf(v0[0]); o[1] = f2bf(v0[1]); o[2] = f2bf(v0[2]); o[3] = f2bf(v0[3]);
            o[4] = f2bf(v1[0]); o[5] = f2bf(v1[1]); o[6] = f2bf(v1[2]); o[7] = f2bf(v1[3]);
            *(ushort8v*)(xb + (size_t)row * 1024 + ch * 8) = *(ushort8v*)o;
        }
    } else if (b < 256 + 512) {
        weff_tile<1024, 1024>(sk0, dk0, w0t, smem.wtile, b - 256);
    } else if (b < 256 + 512 + 256) {
        weff_tile<1024, 512>(sk1, dk1, w1t, smem.wtile, b - (256 + 512));
    } else if (b < 256 + 512 + 256 + 64) {
        weff_tile<512, 256>(sk2, dk2, w2t, smem.wtile, b - (256 + 512 + 256));
    } else {
        // deterministic stable counting sort (pure function of `ind`)
        int myind[16];
#pragma unroll
        for (int i = 0; i < 16; ++i) myind[i] = ind[t * 16 + i];
        unsigned short c[NDOM];
#pragma unroll
        for (int d = 0; d < NDOM; ++d) c[d] = 0;
#pragma unroll
        for (int i = 0; i < 16; ++i) c[myind[i]]++;
#pragma unroll
        for (int d = 0; d < NDOM; ++d) smem.sort.cnt[t][d] = c[d];
        __syncthreads();
        if (t < NDOM) {
            int acc = 0;
            for (int ch = 0; ch < 256; ++ch) { smem.sort.base[ch][t] = acc; acc += smem.sort.cnt[ch][t]; }
            smem.sort.dom_total[t] = acc;
        }
        __syncthreads();
        if (t == 0) {
            int acc = 0;
            for (int d = 0; d < NDOM; ++d) { smem.sort.dom_off[d] = acc; acc += smem.sort.dom_total[d]; }
            smem.sort.dom_off[NDOM] = acc;
        }
        __syncthreads();
        int pos[NDOM];
#pragma unroll
        for (int d = 0; d < NDOM; ++d) pos[d] = smem.sort.dom_off[d] + smem.sort.base[t][d];
#pragma unroll
        for (int i = 0; i < 16; ++i) {
            int dm = myind[i];
            rowidx[pos[dm]++] = t * 16 + i;
        }
        if (t <= NDOM) offsets[t] = smem.sort.dom_off[t];
    }
}

// ---------------------------------------------------------------------------
// Grouped GEMM: 2x2 waves, wave tile (FM*16)x(FN*16), double-buffered LDS,
// one barrier per k-tile — EXACT round-0 structure (best measured, 187.4us).
// Frag ds_reads are hoisted BEFORE the next tile's DMA issue so no
// conservative vmcnt wait can land mid-loop; the barrier's vmcnt(0) drain
// waits only for latency not covered by the compute phase.
// ---------------------------------------------------------------------------
template <int FM, int FN, int MSLOTS, int K, int N, bool GATHER, bool SCATTER>
__launch_bounds__(256)
__global__ void star_gemm(const unsigned short* __restrict__ Ab,
                          const unsigned short* __restrict__ Wt,
                          const float* __restrict__ sb,
                          const float* __restrict__ db,
                          float* __restrict__ OutF,
                          unsigned short* __restrict__ OutB,
                          const int* __restrict__ offsets,
                          const int* __restrict__ rowidx) {
    constexpr int BM = 32 * FM;
    constexpr int BN = 32 * FN;
    constexpr int NK = K / 64;     // 64-wide k tiles (NK even)
    constexpr int AI = BM / 32;    // A dma instrs per wave (1KB each)
    constexpr int WI = BN / 32;    // W dma instrs per wave

    __shared__ __align__(128) unsigned short As[2][BM * 64];
    __shared__ __align__(128) unsigned short Ws[2][BN * 64];

    const int gid = blockIdx.x;
    const int d = gid & 7;                      // domain -> XCD round-robin
    const int mslot = (gid >> 3) % MSLOTS;
    const int n0 = (gid / (8 * MSLOTS)) * BN;

    const int bstart = offsets[d];
    const int bend = offsets[d + 1];
    const int bsize = bend - bstart;

    const int tid = threadIdx.x;
    const int lane = tid & 63;
    const int w = tid >> 6;
    const int wy = w >> 1;
    const int wx = w & 1;
    const int lm = lane & 15;
    const int quad = lane >> 4;

    const int lrow = lane >> 3;    // DMA: row within 8-row group
    const int phys = lane & 7;     // DMA: physical LDS chunk

    float bias[FN];
#pragma unroll
    for (int j = 0; j < FN; ++j) {
        int n = n0 + wx * FN * 16 + j * 16 + lm;
        bias[j] = sb[n] + db[d * N + n];
    }

    // W dma sources (loop-invariant)
    const unsigned short* wsrc[WI];
#pragma unroll
    for (int j = 0; j < WI; ++j) {
        int nr0 = (w * WI + j) * 8;
        int nn = nr0 + lrow;
        int ch = phys ^ (nn & 7);
        wsrc[j] = Wt + ((size_t)d * N + n0 + nn) * K + ch * 8;
    }

    for (int mt = mslot; mt * BM < bsize; mt += MSLOTS) {
        const int row_start = bstart + mt * BM;

        const unsigned short* asrc[AI];
#pragma unroll
        for (int j = 0; j < AI; ++j) {
            int m0 = (w * AI + j) * 8;
            int mm = m0 + lrow;
            int ch = phys ^ (mm & 7);
            int p = row_start + mm; if (p >= bend) p = bend - 1;
            int src = GATHER ? rowidx[p] : p;
            asrc[j] = Ab + (size_t)src * K + ch * 8;
        }

        auto dma_tiles = [&](int kt, int buf) {
            const int k0 = kt * 64;
#pragma unroll
            for (int j = 0; j < AI; ++j)
                dma16(asrc[j] + k0, &As[buf][(w * AI + j) * 512]);
#pragma unroll
            for (int j = 0; j < WI; ++j)
                dma16(wsrc[j] + k0, &Ws[buf][(w * WI + j) * 512]);
        };

        floatx4 acc[FM][FN];
#pragma unroll
        for (int i = 0; i < FM; ++i)
#pragma unroll
            for (int j = 0; j < FN; ++j) acc[i][j] = floatx4{0.f, 0.f, 0.f, 0.f};

        dma_tiles(0, 0);                       // prologue (buf0 safe: see barrier layout)
        for (int kt = 0; kt < NK; ++kt) {
            const int buf = kt & 1;
            __syncthreads();                   // drains dma(kt); prev compute done

            // hoist ALL frag reads before issuing next DMA
            short8 av[2][FM], wv[2][FN];
#pragma unroll
            for (int kk = 0; kk < 2; ++kk) {
#pragma unroll
                for (int i = 0; i < FM; ++i) {
                    int m = wy * FM * 16 + i * 16 + lm;
                    int pc = (kk * 4 + quad) ^ (m & 7);
                    av[kk][i] = *(const short8*)&As[buf][m * 64 + pc * 8];
                }
#pragma unroll
                for (int j = 0; j < FN; ++j) {
                    int n = wx * FN * 16 + j * 16 + lm;
                    int pc = (kk * 4 + quad) ^ (n & 7);
                    wv[kk][j] = *(const short8*)&Ws[buf][n * 64 + pc * 8];
                }
            }
            if (kt + 1 < NK) dma_tiles(kt + 1, 1 - buf);   // in flight across MFMA
#pragma unroll
            for (int kk = 0; kk < 2; ++kk)
#pragma unroll
                for (int i = 0; i < FM; ++i)
#pragma unroll
                    for (int j = 0; j < FN; ++j)
                        acc[i][j] = __builtin_amdgcn_mfma_f32_16x16x32_bf16(
                            av[kk][i], wv[kk][j], acc[i][j], 0, 0, 0);
        }

        // epilogue: bias + relu; C layout col=lane&15, row=quad*4+reg
#pragma unroll
        for (int i = 0; i < FM; ++i) {
#pragma unroll
            for (int rg = 0; rg < 4; ++rg) {
                int m = wy * FM * 16 + i * 16 + quad * 4 + rg;
                int p = row_start + m;
                if (p < bend) {
                    if constexpr (SCATTER) {
                        int orow = rowidx[p];
#pragma unroll
                        for (int j = 0; j < FN; ++j) {
                            int n = n0 + wx * FN * 16 + j * 16 + lm;
                            float v = acc[i][j][rg] + bias[j];
                            OutF[(size_t)orow * N + n] = v > 0.f ? v : 0.f;
                        }
                    } else {
#pragma unroll
                        for (int j = 0; j < FN; ++j) {
                            int n = n0 + wx * FN * 16 + j * 16 + lm;
                            float v = acc[i][j][rg] + bias[j];
                            OutB[(size_t)p * N + n] = f2bf(v > 0.f ? v : 0.f);
                        }
                    }
                }
            }
        }
    }
}

extern "C" void kernel_launch(void* const* d_in, const int* in_sizes, int n_in,
                              void* d_out, int out_size, void* d_ws, size_t ws_size,
                              hipStream_t stream) {
    const float* x = (const float*)d_in[0];
    const int* ind = (const int*)d_in[1];
    const float* sk0 = (const float*)d_in[2];
    const float* sb0 = (const float*)d_in[3];
    const float* dk0 = (const float*)d_in[4];
    const float* db0 = (const float*)d_in[5];
    const float* sk1 = (const float*)d_in[6];
    const float* sb1 = (const float*)d_in[7];
    const float* dk1 = (const float*)d_in[8];
    const float* db1 = (const float*)d_in[9];
    const float* sk2 = (const float*)d_in[10];
    const float* sb2 = (const float*)d_in[11];
    const float* dk2 = (const float*)d_in[12];
    const float* db2 = (const float*)d_in[13];
    float* out = (float*)d_out;

    // workspace layout (~46 MB)
    char* ws = (char*)d_ws;
    int* offsets = (int*)ws;                                      // 64 B
    int* rowidx = (int*)(ws + 256);                               // 16 KB
    unsigned short* xb  = (unsigned short*)(ws + 32768);          // 8 MB  bf16 x, ORIGINAL order
    unsigned short* h1  = xb + (size_t)NROWS * 1024;              // 8 MB  bucket order
    unsigned short* h2  = h1 + (size_t)NROWS * 1024;              // 4 MB  bucket order
    unsigned short* w0t = h2 + (size_t)NROWS * 512;               // 16 MB [d][n=1024][k=1024]
    unsigned short* w1t = w0t + (size_t)NDOM * 1024 * 1024;       // 8 MB  [d][n=512][k=1024]
    unsigned short* w2t = w1t + (size_t)NDOM * 512 * 1024;        // 2 MB  [d][n=256][k=512]

    // fused: xb cvt + 3x weight transpose-precompute + bucket sort (1 dispatch)
    precompute_kernel<<<256 + 512 + 256 + 64 + 1, 256, 0, stream>>>(
        x, ind, sk0, dk0, sk1, dk1, sk2, dk2, xb, w0t, w1t, w2t, offsets, rowidx);

    // L0: 64x64 tiles, 8d x 8m x 16n = 1024 blocks, rowidx-gather DMA
    star_gemm<2, 2, 8, 1024, 1024, true, false><<<1024, 256, 0, stream>>>(
        xb, w0t, sb0, db0, nullptr, h1, offsets, rowidx);
    // L1: 64x64 tiles, 8d x 8m x 8n = 512 blocks
    star_gemm<2, 2, 8, 1024, 512, false, false><<<512, 256, 0, stream>>>(
        h1, w1t, sb1, db1, nullptr, h2, offsets, rowidx);
    // L2: 32x64 tiles, 8d x 16m x 4n = 512 blocks (scatter to fp32 out)
    star_gemm<1, 2, 16, 512, 256, false, true><<<512, 256, 0, stream>>>(
        h2, w2t, sb2, db2, out, nullptr, offsets, rowidx);
}

// Round 10
// 185.705 us; speedup vs baseline: 1.1269x; 1.0167x over previous
//
#include <hip/hip_runtime.h>

#define NROWS 4096
#define NDOM 8

typedef short short8 __attribute__((ext_vector_type(8)));
typedef float floatx4 __attribute__((ext_vector_type(4)));
typedef unsigned short ushort8v __attribute__((ext_vector_type(8)));
typedef unsigned short ushort4v __attribute__((ext_vector_type(4)));

__device__ __forceinline__ unsigned short f2bf(float f) {
    union { float f; unsigned u; } v; v.f = f;
    unsigned r = v.u + 0x7FFFu + ((v.u >> 16) & 1u);  // RNE
    return (unsigned short)(r >> 16);
}

// async global->LDS, 16B per lane; dest = wave-uniform base + lane*16,
// source address may be per-lane (gather is legal on the source side).
__device__ __forceinline__ void dma16(const void* g, void* l) {
    __builtin_amdgcn_global_load_lds(
        (const __attribute__((address_space(1))) unsigned*)g,
        (__attribute__((address_space(3))) unsigned*)l, 16, 0, 0);
}

// ---------------------------------------------------------------------------
// weff transpose tile v2: (d, 128 n, 128 k) of bf16(sk*dk) -> wt[d][n][k].
// R7/R8 falsified issue-rate/occupancy/in-flight theories for the 2.3TB/s
// precompute wall; surviving theory = DRAM page locality (256B read granule
// at 4KB stride). This version reads 512B contiguous per row per instr
// (lane n-window x float4, 2 rows/instr), in-register 4x4 micro-transpose,
// vector b64 LDS writes with XOR swizzle (<=2 lanes/bank). Same 32KB LDS,
// same 832-block budget as the verified R0 structure; phase-B global stores
// keep the verified 256B coalescing.
// LDS layout: element (n,k) at ushort index n*128 + (((k>>2) ^ (n>>2))*4) + (k&3).
// ---------------------------------------------------------------------------
template <int K, int N>
__device__ __forceinline__ void weff_tile128(const float* __restrict__ sk,
                                             const float* __restrict__ dk,
                                             unsigned short* __restrict__ wt,
                                             unsigned short* __restrict__ lds,
                                             int local) {
    const int d = local & 7;
    const int rest = local >> 3;
    const int kt = rest & (K / 128 - 1);
    const int nt = rest / (K / 128);
    const int k0 = kt * 128;
    const int n0 = nt * 128;

    const int t = threadIdx.x;
    const int lane = t & 63;
    const int wv = t >> 6;           // wave owns k-rows [wv*32, wv*32+32)
    const int rh = lane >> 5;        // row-half within instruction
    const int nw = lane & 31;        // n-window: n = nw*4 + j

    // phase A: 512B-contiguous row reads, 4x4 in-register transpose, b64 LDS writes
#pragma unroll
    for (int g = 0; g < 4; ++g) {
        const int base = wv * 32 + rh * 16 + g * 4;   // 4 consecutive k rows
        floatx4 sv[4], dv[4];
#pragma unroll
        for (int i = 0; i < 4; ++i) {
            const int k = k0 + base + i;
            sv[i] = *(const floatx4*)&sk[(size_t)k * N + n0 + nw * 4];
            dv[i] = *(const floatx4*)&dk[((size_t)d * K + k) * N + n0 + nw * 4];
        }
        const int c = base >> 2;                      // k-chunk index 0..31
        const int phys = c ^ nw;                      // XOR swizzle
#pragma unroll
        for (int j = 0; j < 4; ++j) {
            ushort4v ch;
            ch[0] = f2bf(sv[0][j] * dv[0][j]);
            ch[1] = f2bf(sv[1][j] * dv[1][j]);
            ch[2] = f2bf(sv[2][j] * dv[2][j]);
            ch[3] = f2bf(sv[3][j] * dv[3][j]);
            const int n = nw * 4 + j;
            *(ushort4v*)&lds[n * 128 + phys * 4] = ch;
        }
    }
    __syncthreads();

    // phase B: gather k-runs from swizzled chunks, 256B-coalesced global stores
    const int cp = t & 15;           // 16B unit: k = cp*8..cp*8+7
    const int nr = t >> 4;
#pragma unroll
    for (int it = 0; it < 8; ++it) {
        const int n = it * 16 + nr;
        const int s = n >> 2;
        ushort4v a = *(ushort4v*)&lds[n * 128 + ((2 * cp) ^ s) * 4];
        ushort4v b = *(ushort4v*)&lds[n * 128 + ((2 * cp + 1) ^ s) * 4];
        ushort8v o;
        o[0] = a[0]; o[1] = a[1]; o[2] = a[2]; o[3] = a[3];
        o[4] = b[0]; o[5] = b[1]; o[6] = b[2]; o[7] = b[3];
        *(ushort8v*)(wt + ((size_t)d * N + n0 + n) * K + k0 + cp * 8) = o;
    }
}

// ---------------------------------------------------------------------------
// Fused precompute dispatch (R0/R9 block budget, weff kernel swapped):
//   blocks [0,256)        : xb = bf16(x), ORIGINAL row order
//   blocks [256,768)      : w0t (8kt x 8nt x 8d = 512)
//   blocks [768,1024)     : w1t (8kt x 4nt x 8d = 256)
//   blocks [1024,1088)    : w2t (4kt x 2nt x 8d = 64)
//   block 1088            : deterministic counting-sort -> offsets, rowidx
// ---------------------------------------------------------------------------
__global__ void precompute_kernel(const float* __restrict__ x,
                                  const int* __restrict__ ind,
                                  const float* __restrict__ sk0, const float* __restrict__ dk0,
                                  const float* __restrict__ sk1, const float* __restrict__ dk1,
                                  const float* __restrict__ sk2, const float* __restrict__ dk2,
                                  unsigned short* __restrict__ xb,
                                  unsigned short* __restrict__ w0t,
                                  unsigned short* __restrict__ w1t,
                                  unsigned short* __restrict__ w2t,
                                  int* __restrict__ offsets,
                                  int* __restrict__ rowidx) {
    __shared__ union SMem {
        unsigned short wtile[128 * 128];                // 32KB transpose buffer
        struct {
            unsigned short cnt[256][NDOM];
            int base[256][NDOM];
            int dom_total[NDOM];
            int dom_off[NDOM + 1];
        } sort;
    } smem;

    const int b = blockIdx.x;
    const int t = threadIdx.x;

    if (b < 256) {
        // xb: bf16(x) in original row order, fully coalesced both sides
#pragma unroll
        for (int pass = 0; pass < 8; ++pass) {
            int row = b * 16 + pass * 2 + (t >> 7);
            int ch = t & 127;                       // 8-elem chunk
            const float* src = x + (size_t)row * 1024 + ch * 8;
            floatx4 v0 = *(const floatx4*)src;
            floatx4 v1 = *(const floatx4*)(src + 4);
            unsigned short o[8];
            o[0] = f2bf(v0[0]); o[1] = f2bf(v0[1]); o[2] = f2bf(v0[2]); o[3] = f2bf(v0[3]);
            o[4] = f2bf(v1[0]); o[5] = f2bf(v1[1]); o[6] = f2bf(v1[2]); o[7] = f2bf(v1[3]);
            *(ushort8v*)(xb + (size_t)row * 1024 + ch * 8) = *(ushort8v*)o;
        }
    } else if (b < 256 + 512) {
        weff_tile128<1024, 1024>(sk0, dk0, w0t, smem.wtile, b - 256);
    } else if (b < 256 + 512 + 256) {
        weff_tile128<1024, 512>(sk1, dk1, w1t, smem.wtile, b - (256 + 512));
    } else if (b < 256 + 512 + 256 + 64) {
        weff_tile128<512, 256>(sk2, dk2, w2t, smem.wtile, b - (256 + 512 + 256));
    } else {
        // deterministic stable counting sort (pure function of `ind`)
        int myind[16];
#pragma unroll
        for (int i = 0; i < 16; ++i) myind[i] = ind[t * 16 + i];
        unsigned short c[NDOM];
#pragma unroll
        for (int d = 0; d < NDOM; ++d) c[d] = 0;
#pragma unroll
        for (int i = 0; i < 16; ++i) c[myind[i]]++;
#pragma unroll
        for (int d = 0; d < NDOM; ++d) smem.sort.cnt[t][d] = c[d];
        __syncthreads();
        if (t < NDOM) {
            int acc = 0;
            for (int ch = 0; ch < 256; ++ch) { smem.sort.base[ch][t] = acc; acc += smem.sort.cnt[ch][t]; }
            smem.sort.dom_total[t] = acc;
        }
        __syncthreads();
        if (t == 0) {
            int acc = 0;
            for (int d = 0; d < NDOM; ++d) { smem.sort.dom_off[d] = acc; acc += smem.sort.dom_total[d]; }
            smem.sort.dom_off[NDOM] = acc;
        }
        __syncthreads();
        int pos[NDOM];
#pragma unroll
        for (int d = 0; d < NDOM; ++d) pos[d] = smem.sort.dom_off[d] + smem.sort.base[t][d];
#pragma unroll
        for (int i = 0; i < 16; ++i) {
            int dm = myind[i];
            rowidx[pos[dm]++] = t * 16 + i;
        }
        if (t <= NDOM) offsets[t] = smem.sort.dom_off[t];
    }
}

// ---------------------------------------------------------------------------
// Grouped GEMM: 2x2 waves, wave tile (FM*16)x(FN*16), double-buffered LDS,
// one barrier per k-tile — EXACT round-0/round-9 structure (best measured).
// ---------------------------------------------------------------------------
template <int FM, int FN, int MSLOTS, int K, int N, bool GATHER, bool SCATTER>
__launch_bounds__(256)
__global__ void star_gemm(const unsigned short* __restrict__ Ab,
                          const unsigned short* __restrict__ Wt,
                          const float* __restrict__ sb,
                          const float* __restrict__ db,
                          float* __restrict__ OutF,
                          unsigned short* __restrict__ OutB,
                          const int* __restrict__ offsets,
                          const int* __restrict__ rowidx) {
    constexpr int BM = 32 * FM;
    constexpr int BN = 32 * FN;
    constexpr int NK = K / 64;     // 64-wide k tiles (NK even)
    constexpr int AI = BM / 32;    // A dma instrs per wave (1KB each)
    constexpr int WI = BN / 32;    // W dma instrs per wave

    __shared__ __align__(128) unsigned short As[2][BM * 64];
    __shared__ __align__(128) unsigned short Ws[2][BN * 64];

    const int gid = blockIdx.x;
    const int d = gid & 7;                      // domain -> XCD round-robin
    const int mslot = (gid >> 3) % MSLOTS;
    const int n0 = (gid / (8 * MSLOTS)) * BN;

    const int bstart = offsets[d];
    const int bend = offsets[d + 1];
    const int bsize = bend - bstart;

    const int tid = threadIdx.x;
    const int lane = tid & 63;
    const int w = tid >> 6;
    const int wy = w >> 1;
    const int wx = w & 1;
    const int lm = lane & 15;
    const int quad = lane >> 4;

    const int lrow = lane >> 3;    // DMA: row within 8-row group
    const int phys = lane & 7;     // DMA: physical LDS chunk

    float bias[FN];
#pragma unroll
    for (int j = 0; j < FN; ++j) {
        int n = n0 + wx * FN * 16 + j * 16 + lm;
        bias[j] = sb[n] + db[d * N + n];
    }

    // W dma sources (loop-invariant)
    const unsigned short* wsrc[WI];
#pragma unroll
    for (int j = 0; j < WI; ++j) {
        int nr0 = (w * WI + j) * 8;
        int nn = nr0 + lrow;
        int ch = phys ^ (nn & 7);
        wsrc[j] = Wt + ((size_t)d * N + n0 + nn) * K + ch * 8;
    }

    for (int mt = mslot; mt * BM < bsize; mt += MSLOTS) {
        const int row_start = bstart + mt * BM;

        const unsigned short* asrc[AI];
#pragma unroll
        for (int j = 0; j < AI; ++j) {
            int m0 = (w * AI + j) * 8;
            int mm = m0 + lrow;
            int ch = phys ^ (mm & 7);
            int p = row_start + mm; if (p >= bend) p = bend - 1;
            int src = GATHER ? rowidx[p] : p;
            asrc[j] = Ab + (size_t)src * K + ch * 8;
        }

        auto dma_tiles = [&](int kt, int buf) {
            const int k0 = kt * 64;
#pragma unroll
            for (int j = 0; j < AI; ++j)
                dma16(asrc[j] + k0, &As[buf][(w * AI + j) * 512]);
#pragma unroll
            for (int j = 0; j < WI; ++j)
                dma16(wsrc[j] + k0, &Ws[buf][(w * WI + j) * 512]);
        };

        floatx4 acc[FM][FN];
#pragma unroll
        for (int i = 0; i < FM; ++i)
#pragma unroll
            for (int j = 0; j < FN; ++j) acc[i][j] = floatx4{0.f, 0.f, 0.f, 0.f};

        dma_tiles(0, 0);                       // prologue (buf0 safe: see barrier layout)
        for (int kt = 0; kt < NK; ++kt) {
            const int buf = kt & 1;
            __syncthreads();                   // drains dma(kt); prev compute done

            // hoist ALL frag reads before issuing next DMA
            short8 av[2][FM], wv[2][FN];
#pragma unroll
            for (int kk = 0; kk < 2; ++kk) {
#pragma unroll
                for (int i = 0; i < FM; ++i) {
                    int m = wy * FM * 16 + i * 16 + lm;
                    int pc = (kk * 4 + quad) ^ (m & 7);
                    av[kk][i] = *(const short8*)&As[buf][m * 64 + pc * 8];
                }
#pragma unroll
                for (int j = 0; j < FN; ++j) {
                    int n = wx * FN * 16 + j * 16 + lm;
                    int pc = (kk * 4 + quad) ^ (n & 7);
                    wv[kk][j] = *(const short8*)&Ws[buf][n * 64 + pc * 8];
                }
            }
            if (kt + 1 < NK) dma_tiles(kt + 1, 1 - buf);   // in flight across MFMA
#pragma unroll
            for (int kk = 0; kk < 2; ++kk)
#pragma unroll
                for (int i = 0; i < FM; ++i)
#pragma unroll
                    for (int j = 0; j < FN; ++j)
                        acc[i][j] = __builtin_amdgcn_mfma_f32_16x16x32_bf16(
                            av[kk][i], wv[kk][j], acc[i][j], 0, 0, 0);
        }

        // epilogue: bias + relu; C layout col=lane&15, row=quad*4+reg
#pragma unroll
        for (int i = 0; i < FM; ++i) {
#pragma unroll
            for (int rg = 0; rg < 4; ++rg) {
                int m = wy * FM * 16 + i * 16 + quad * 4 + rg;
                int p = row_start + m;
                if (p < bend) {
                    if constexpr (SCATTER) {
                        int orow = rowidx[p];
#pragma unroll
                        for (int j = 0; j < FN; ++j) {
                            int n = n0 + wx * FN * 16 + j * 16 + lm;
                            float v = acc[i][j][rg] + bias[j];
                            OutF[(size_t)orow * N + n] = v > 0.f ? v : 0.f;
                        }
                    } else {
#pragma unroll
                        for (int j = 0; j < FN; ++j) {
                            int n = n0 + wx * FN * 16 + j * 16 + lm;
                            float v = acc[i][j][rg] + bias[j];
                            OutB[(size_t)p * N + n] = f2bf(v > 0.f ? v : 0.f);
                        }
                    }
                }
            }
        }
    }
}

extern "C" void kernel_launch(void* const* d_in, const int* in_sizes, int n_in,
                              void* d_out, int out_size, void* d_ws, size_t ws_size,
                              hipStream_t stream) {
    const float* x = (const float*)d_in[0];
    const int* ind = (const int*)d_in[1];
    const float* sk0 = (const float*)d_in[2];
    const float* sb0 = (const float*)d_in[3];
    const float* dk0 = (const float*)d_in[4];
    const float* db0 = (const float*)d_in[5];
    const float* sk1 = (const float*)d_in[6];
    const float* sb1 = (const float*)d_in[7];
    const float* dk1 = (const float*)d_in[8];
    const float* db1 = (const float*)d_in[9];
    const float* sk2 = (const float*)d_in[10];
    const float* sb2 = (const float*)d_in[11];
    const float* dk2 = (const float*)d_in[12];
    const float* db2 = (const float*)d_in[13];
    float* out = (float*)d_out;

    // workspace layout (~46 MB)
    char* ws = (char*)d_ws;
    int* offsets = (int*)ws;                                      // 64 B
    int* rowidx = (int*)(ws + 256);                               // 16 KB
    unsigned short* xb  = (unsigned short*)(ws + 32768);          // 8 MB  bf16 x, ORIGINAL order
    unsigned short* h1  = xb + (size_t)NROWS * 1024;              // 8 MB  bucket order
    unsigned short* h2  = h1 + (size_t)NROWS * 1024;              // 4 MB  bucket order
    unsigned short* w0t = h2 + (size_t)NROWS * 512;               // 16 MB [d][n=1024][k=1024]
    unsigned short* w1t = w0t + (size_t)NDOM * 1024 * 1024;       // 8 MB  [d][n=512][k=1024]
    unsigned short* w2t = w1t + (size_t)NDOM * 512 * 1024;        // 2 MB  [d][n=256][k=512]

    // fused: xb cvt + 3x weight transpose-precompute + bucket sort (1 dispatch)
    precompute_kernel<<<256 + 512 + 256 + 64 + 1, 256, 0, stream>>>(
        x, ind, sk0, dk0, sk1, dk1, sk2, dk2, xb, w0t, w1t, w2t, offsets, rowidx);

    // L0: 64x64 tiles, 8d x 8m x 16n = 1024 blocks, rowidx-gather DMA
    star_gemm<2, 2, 8, 1024, 1024, true, false><<<1024, 256, 0, stream>>>(
        xb, w0t, sb0, db0, nullptr, h1, offsets, rowidx);
    // L1: 64x64 tiles, 8d x 8m x 8n = 512 blocks
    star_gemm<2, 2, 8, 1024, 512, false, false><<<512, 256, 0, stream>>>(
        h1, w1t, sb1, db1, nullptr, h2, offsets, rowidx);
    // L2: 32x64 tiles, 8d x 16m x 4n = 512 blocks (scatter to fp32 out)
    star_gemm<1, 2, 16, 512, 256, false, true><<<512, 256, 0, stream>>>(
        h2, w2t, sb2, db2, out, nullptr, offsets, rowidx);
}